// Round 9
// baseline (220.688 us; speedup 1.0000x reference)
//
#include <hip/hip_runtime.h>

// PrimaryCaps implicit GEMM, round 9: T3-minimum 2-phase LDS staging.
// r7/r8 proved register-prefetch is compiler-collapsed (identical binaries,
// MfmaUtil 21%). This is the guide's proven structure: global_load_lds(16B)
// double-buffered staging + ds_read frags + 1 barrier/K-step.
//   GEMM: M=100352, N=392(pad 448), K=1312. Block tile 512x64, 4 waves,
//   wave tile 128x64 (4m x 2n frags). K-step 32 = 2 taps x 16ch.
//   A-tile LDS XOR-swizzled BOTH sides (stage source + read addr), rule 21.

typedef __attribute__((ext_vector_type(8)))  short short8;
typedef __attribute__((ext_vector_type(16))) float f32x16;

constexpr int Bn = 128, Units = 49, Cap = 8, OW = 28, HWp = 784;
constexpr int Nn = 392, Npad = 448;
constexpr int BM = 512, BNt = 64, NB = 7;      // grid: 196 mb x 7 nb = 1372
constexpr int NKS = 41;                        // K-steps of 32 (82 tap-slots)
constexpr size_t XW_BYTES = (size_t)Bn * 64 * 64 * 16 * 2;      // 16,777,216
constexpr size_t BW_BYTES = (size_t)NKS * 4 * Npad * 8 * 2;     // 1,175,552

__device__ inline unsigned short f2bf(float f) {
    unsigned u = __float_as_uint(f);
    u += 0x7FFF + ((u >> 16) & 1);
    return (unsigned short)(u >> 16);
}

__device__ __forceinline__ void gload16(const void* g, void* l) {
    __builtin_amdgcn_global_load_lds(
        (const __attribute__((address_space(1))) unsigned int*)g,
        (__attribute__((address_space(3))) unsigned int*)l, 16, 0, 0);
}

// ---- prep 1: x NCHW f32 -> NHWC bf16 (verified) -----------------------------
__global__ __launch_bounds__(256) void prep_x(const float* __restrict__ x,
                                              unsigned short* __restrict__ xw) {
    __shared__ unsigned short tile[64 * 16];   // [x][c]
    const int b = blockIdx.x >> 6, y = blockIdx.x & 63;
    const int t = threadIdx.x;
    const int c = t >> 4, x0 = (t & 15) * 4;
    const float4 v = *(const float4*)(x + (((size_t)b * 16 + c) * 64 + y) * 64 + x0);
    tile[(x0 + 0) * 16 + c] = f2bf(v.x);
    tile[(x0 + 1) * 16 + c] = f2bf(v.y);
    tile[(x0 + 2) * 16 + c] = f2bf(v.z);
    tile[(x0 + 3) * 16 + c] = f2bf(v.w);
    __syncthreads();
    const ushort4 o = *(const ushort4*)&tile[t * 4];
    *(ushort4*)(xw + (size_t)blockIdx.x * 1024 + t * 4) = o;
}

// ---- prep 2: W -> bw[ks][t*2+h][448 n] 16B chunks (8ch each) ----------------
__global__ __launch_bounds__(256) void prep_w(const float* __restrict__ W,
                                              unsigned short* __restrict__ bw) {
    const int idx = blockIdx.x * 256 + threadIdx.x;   // chunk id
    if (idx >= NKS * 4 * Npad) return;
    const int n    = idx % Npad;
    const int rest = idx / Npad;                      // ks*4 + t*2 + h
    const int h = rest & 1, tt = (rest >> 1) & 1, ks = rest >> 2;
    const int p = ks * 2 + tt;                        // tap slot
    unsigned short vals[8];
    if (p < 81 && n < Nn) {
#pragma unroll
        for (int j = 0; j < 8; ++j)
            vals[j] = f2bf(W[(size_t)(n * 16 + h * 8 + j) * 81 + p]);
    } else {
#pragma unroll
        for (int j = 0; j < 8; ++j) vals[j] = 0;
    }
    *(ushort4*)(bw + (size_t)idx * 8)     = make_ushort4(vals[0], vals[1], vals[2], vals[3]);
    *(ushort4*)(bw + (size_t)idx * 8 + 4) = make_ushort4(vals[4], vals[5], vals[6], vals[7]);
}

// ---- main -------------------------------------------------------------------
#define MFMA32(A, B, C) __builtin_amdgcn_mfma_f32_32x32x16_bf16(A, B, C, 0, 0, 0)

constexpr int ABUF = 32768;                    // A tile bytes (512 rows x 64B)
constexpr int LBUF = ABUF + 4096;              // + B tile (256 chunks x 16B)

__global__ __launch_bounds__(256, 2) void pcaps_lds(
    const unsigned short* __restrict__ xw,
    const unsigned short* __restrict__ bw,
    const float* __restrict__ bias,
    float* __restrict__ out)
{
    __shared__ __align__(16) char lds[2][LBUF];

    const int t = threadIdx.x;
    // bijective XCD swizzle (m204): nwg=1372, 1372%8=4
    const int nwg = gridDim.x;
    const int q8 = nwg >> 3, r8 = nwg & 7;
    const int xcd = blockIdx.x & 7, idx8 = blockIdx.x >> 3;
    const int wgid = (xcd < r8 ? xcd * (q8 + 1) : r8 * (q8 + 1) + (xcd - r8) * q8) + idx8;
    const int nb = wgid % NB, mb = wgid / NB;
    const int n0 = nb * BNt;

    const int w = t >> 6, l = t & 63;
    const int r = l & 31, h = l >> 5;

    // ---- staging precompute: 8 A-chunks + 1 B-chunk per thread per K-step
    // A LDS slot q = t + 256*it holds data(row=q>>2, piece=(q&3)^((row>>1)&3))
    // piece = tq*2 + hq  (tap-of-pair, channel-half)
    int arow_off[8];                           // byte base into xw (incl. hq*16)
    int asel[8];                               // tq
#pragma unroll
    for (int it = 0; it < 8; ++it) {
        const int q = t + 256 * it;
        const int row = q >> 2;
        const int piece = (q & 3) ^ ((row >> 1) & 3);
        const int tq = piece >> 1, hq = piece & 1;
        const int m = mb * BM + row;
        const int b = m / HWp;
        const int hw = m - b * HWp;
        const int oy = hw / OW, ox = hw - oy * OW;
        arow_off[it] = b * 131072 + oy * 4096 + ox * 64 + hq * 16;
        asel[it] = tq;
    }
    // B: wave w stages piece-group w; global byte = ((ks*4+w)*448 + n0+l)*16
    const int bglob0 = (w * Npad + n0 + l) * 16;
    constexpr int bstep = 4 * Npad * 16;       // 28672 per K-step

    // ---- fragment-read LDS byte offsets (precomputed)
    // A: cid0 = (row*4 + h) ^ ((row>>1)&3); slot tt -> cid0 ^ (tt<<1)
    int aoff[4][2];
#pragma unroll
    for (int mi = 0; mi < 4; ++mi) {
        const int row = w * 128 + mi * 32 + r;
        const int cid0 = (row * 4 + h) ^ ((row >> 1) & 3);
        aoff[mi][0] = cid0 * 16;
        aoff[mi][1] = (cid0 ^ 2) * 16;
    }
    int boff[2][2];
#pragma unroll
    for (int ni = 0; ni < 2; ++ni)
#pragma unroll
        for (int tt = 0; tt < 2; ++tt)
            boff[ni][tt] = ABUF + ((tt * 2 + h) * 64 + ni * 32 + r) * 16;

    f32x16 acc[4][2];
#pragma unroll
    for (int mi = 0; mi < 4; ++mi)
#pragma unroll
        for (int ni = 0; ni < 2; ++ni)
#pragma unroll
            for (int e = 0; e < 16; ++e) acc[mi][ni][e] = 0.f;

    const char* __restrict__ xcc = (const char*)xw;
    const char* __restrict__ bcc = (const char*)bw;

    auto stage = [&](char* base, int o0, int o1, int bks) {
#pragma unroll
        for (int it = 0; it < 8; ++it)
            gload16(xcc + (arow_off[it] + (asel[it] ? o1 : o0)),
                    base + (t + 256 * it) * 16);
        gload16(bcc + (bglob0 + bks), base + ABUF + t * 16);
    };

    // prologue: K-step 0 (taps 0,1 -> offsets 0, 32)
    stage(lds[0], 0, 32, 0);
    __syncthreads();

    int ky = 0, kx = 2;                        // tap 2*(ks=1)
    int cur = 0;
    for (int ks = 0; ks < NKS; ++ks) {
        if (ks + 1 < NKS) {
            const int o0 = ky * 2048 + kx * 32;
            int kx1 = kx + 1, ky1 = ky;
            if (kx1 == 9) { kx1 = 0; ky1 += 1; }
            const int o1 = ky1 * 2048 + kx1 * 32;   // ks=40: tap81 -> in-slab garbage x B=0
            stage(lds[cur ^ 1], o0, o1, (ks + 1) * bstep);
            kx += 2; if (kx >= 9) { kx -= 9; ky += 1; }
        }

        const char* base = lds[cur];
        short8 afr[4][2], bfr[2][2];
#pragma unroll
        for (int mi = 0; mi < 4; ++mi)
#pragma unroll
            for (int tt = 0; tt < 2; ++tt)
                afr[mi][tt] = *(const short8*)(base + aoff[mi][tt]);
#pragma unroll
        for (int ni = 0; ni < 2; ++ni)
#pragma unroll
            for (int tt = 0; tt < 2; ++tt)
                bfr[ni][tt] = *(const short8*)(base + boff[ni][tt]);

#pragma unroll
        for (int tt = 0; tt < 2; ++tt)
#pragma unroll
            for (int mi = 0; mi < 4; ++mi)
#pragma unroll
                for (int ni = 0; ni < 2; ++ni)
                    acc[mi][ni] = MFMA32(afr[mi][tt], bfr[ni][tt], acc[mi][ni]);

        __syncthreads();                       // drains staging vmcnt + syncs
        cur ^= 1;
    }

    // epilogue (r4/r7-verified math): bias + squash over 8 consecutive n
    float bv[2];
#pragma unroll
    for (int ni = 0; ni < 2; ++ni) {
        const int n = n0 + ni * 32 + r;
        bv[ni] = (n < Nn) ? bias[n] : 0.f;
    }
#pragma unroll
    for (int mi = 0; mi < 4; ++mi) {
#pragma unroll
        for (int ni = 0; ni < 2; ++ni) {
            const int n = n0 + ni * 32 + r;
            const bool nok = (n < Nn);
#pragma unroll
            for (int reg = 0; reg < 16; ++reg) {
                float e = acc[mi][ni][reg] + bv[ni];
                float sq = e * e;
                sq += __shfl_xor(sq, 1);
                sq += __shfl_xor(sq, 2);
                sq += __shfl_xor(sq, 4);
                const float scale = sqrtf(sq) / (1.0f + sq);
                if (nok) {
                    const int rowc = (reg & 3) + 8 * (reg >> 2) + 4 * h;
                    const int m = mb * BM + w * 128 + mi * 32 + rowc;
                    out[(size_t)m * Nn + n] = e * scale;
                }
            }
        }
    }
}

// ---- fallback (round-1 direct conv, known-correct) --------------------------
__global__ __launch_bounds__(128) void pcaps_direct(
    const float* __restrict__ x, const float* __restrict__ W,
    const float* __restrict__ bias, float* __restrict__ out)
{
    const int blk = blockIdx.x;
    const int tile = blk % 7;
    const int u = (blk / 7) % Units;
    const int b = blk / (7 * Units);
    const int hw = tile * 128 + threadIdx.x;
    const bool active = (hw < HWp);
    const int oy = active ? (hw / OW) : 0;
    const int ox = active ? (hw % OW) : 0;
    const float* xb = x + (size_t)b * (16 * 64 * 64) + (size_t)(oy * 2) * 64 + ox * 2;
    const float* wu = W + (size_t)u * (Cap * 1296);
    float acc[Cap];
#pragma unroll
    for (int j = 0; j < Cap; ++j) acc[j] = bias[u * Cap + j];
    for (int c = 0; c < 16; ++c) {
        const float* xcp = xb + c * (64 * 64);
        const float* wc = wu + c * 81;
#pragma unroll
        for (int ky = 0; ky < 9; ++ky) {
            const float* xr = xcp + ky * 64;
            float xv[9];
#pragma unroll
            for (int kx = 0; kx < 9; ++kx) xv[kx] = xr[kx];
#pragma unroll
            for (int kx = 0; kx < 9; ++kx)
#pragma unroll
                for (int j = 0; j < Cap; ++j)
                    acc[j] = fmaf(xv[kx], wc[j * 1296 + ky * 9 + kx], acc[j]);
        }
    }
    if (active) {
        float msq = 0.f;
#pragma unroll
        for (int j = 0; j < Cap; ++j) msq = fmaf(acc[j], acc[j], msq);
        const float scale = sqrtf(msq) / (1.0f + msq);
        float* op = out + (size_t)b * (HWp * Nn) + (size_t)hw * Nn + u * Cap;
        float4 o0, o1;
        o0.x = acc[0] * scale; o0.y = acc[1] * scale; o0.z = acc[2] * scale; o0.w = acc[3] * scale;
        o1.x = acc[4] * scale; o1.y = acc[5] * scale; o1.z = acc[6] * scale; o1.w = acc[7] * scale;
        *reinterpret_cast<float4*>(op) = o0;
        *reinterpret_cast<float4*>(op + 4) = o1;
    }
}

extern "C" void kernel_launch(void* const* d_in, const int* in_sizes, int n_in,
                              void* d_out, int out_size, void* d_ws, size_t ws_size,
                              hipStream_t stream)
{
    const float* x  = (const float*)d_in[0];
    const float* W  = (const float*)d_in[1];
    const float* bs = (const float*)d_in[2];
    float* out      = (float*)d_out;

    if (ws_size < XW_BYTES + BW_BYTES) {
        pcaps_direct<<<Bn * Units * 7, 128, 0, stream>>>(x, W, bs, out);
        return;
    }

    unsigned short* xw = (unsigned short*)d_ws;
    unsigned short* bw = (unsigned short*)((char*)d_ws + XW_BYTES);

    prep_x<<<Bn * 64, 256, 0, stream>>>(x, xw);
    prep_w<<<(NKS * 4 * Npad + 255) / 256, 256, 0, stream>>>(W, bw);
    pcaps_lds<<<(100352 / BM) * NB, 256, 0, stream>>>(xw, bw, bs, out);
}